// Round 6
// baseline (164.805 us; speedup 1.0000x reference)
//
#include <hip/hip_runtime.h>
#include <math.h>

#define NPTS 4096
#define NSMP 10

typedef _Float16 half4 __attribute__((ext_vector_type(4)));
typedef _Float16 half8 __attribute__((ext_vector_type(8)));
typedef float f32x4 __attribute__((ext_vector_type(4)));

// ---------------- single fused kernel: prep (w1,b1,w2,b2 -> Wn,bb) + topk + mlp -------
// R12 post-mortem: spill fully fixed at (1024,5) (WRITE exactly 8.2 MB, VGPR 48) yet
// topk 83.9->83.0 us: spill was never the bottleneck.  The stable signature across ALL
// rounds is total-minus-topk ~= 61-63 us: the serialized 1-block prep_kernel dispatch
// + inter-kernel gap.  Fix: fuse prep into topk.  prep's output (Wn->wl, bb->bl) is
// only read by the epilogue; its compute (256 threads, ~480 fma, 28 KB L3-hot weights)
// runs in waves 12-15 DURING point staging (waves 0-11).  Partials live in an LDS
// union aliased with X (X is dead until pass 1); one extra barrier reduces them into
// wl/bl with the exact original summation order -> bit-identical output.
// prep branch restructured c-outer with wloc10[10] (not wloc[30]) to keep its live set
// ~32 VGPR so the kernel stays <=64 VGPR (2 blocks/CU needs 8 waves/SIMD).
// Filter (unchanged from R12): mfma_f32_16x16x32_f16, 16 waves = 4 query-tiles(16
// rows) x 4 point-slices(1024 pts); fp16 payload + runtime slack; tau = exact
// 10th-smallest of 64 unit-mins (radix-select); f64 re-rank from EXACT f32 coords.
// LDS 74.5 KB -> 2 blocks/CU.
__global__ __launch_bounds__(1024, 5) void topk_kernel(const float* __restrict__ pos,
                                                       const float* __restrict__ w1,
                                                       const float* __restrict__ b1,
                                                       const float* __restrict__ w2,
                                                       const float* __restrict__ b2,
                                                       float* __restrict__ out) {
  __shared__ half4 pts4[NPTS];        // 32 KB: (hx,hy,hz,hsq) per point
  __shared__ __align__(16) float U[7936];  // 31 KB union: part[4][30][64]+bpart[4][64]
                                           //   then X: minbuf(64x65) -> bufi -> trans
  __shared__ half4 a4s[64];           // 0.5 KB: per query row (-2hqx,-2hqy,-2hqz,1)
  __shared__ float wl[30 * 64];       // 7.5 KB Wn
  __shared__ float bl[64];
  __shared__ float taub[64];
  __shared__ float sqqs[64];          // |q|^2 exact (f32) per row
  __shared__ int   cnt[64];
  __shared__ int   nbrT[64][NSMP];    // 2.5 KB      -> total 74.5 KB

  const int b = blockIdx.y, tid = threadIdx.x, lane = tid & 63, wv = tid >> 6;
  const float* pb = pos + (size_t)b * 3 * NPTS;
  const int nb = blockIdx.x * 64;
  float* part = U;                    // [4][30][64] = 7680 floats
  float* bpart = U + 7680;            // [4][64]
  float* X = U;                       // minbuf / trans (4160 floats)

  // ---- phase 0: waves 0-11 stage fp16 points; waves 12-15 do prep partials ----
  if (wv < 12) {
    for (int i = tid; i < NPTS; i += 768) {
      float x = pb[i], y = pb[i + NPTS], z = pb[i + 2 * NPTS];
      float sq = fmaf(z, z, fmaf(y, y, x * x));
      half4 v = {(_Float16)x, (_Float16)y, (_Float16)z, (_Float16)sq};
      pts4[i] = v;
    }
  } else {
    const int t = tid - 768;                 // 0..255
    const int p = t & 63, grp = t >> 6, o0 = grp * 16;  // wave-uniform grp
    const int sg[16] = {0,2,4,6, 3,5,7,9, 1,3,5,7, 2,4,6,8};
    float w2r[16];
    const float* w2p = w2 + p * 64 + o0;     // 16 consecutive floats per lane
    #pragma unroll
    for (int oo = 0; oo < 16; ++oo) w2r[oo] = w2p[oo];
    #pragma unroll 1
    for (int c = 0; c < 3; ++c) {            // c-outer: wloc10 keeps live set small
      float wloc10[10];
      #pragma unroll
      for (int s = 0; s < 10; ++s) wloc10[s] = 0.0f;
      #pragma unroll
      for (int g = 0; g < 4; ++g)
        #pragma unroll
        for (int ii = 0; ii < 2; ++ii)
          #pragma unroll
          for (int jj = 0; jj < 2; ++jj) {
            const int s = sg[g * 4 + ii * 2 + jj];
            const int k = (c + 3 * g) * 4 + ii * 2 + jj;  // w1 flat index (12,2,2)
            float wk = 0.0f;
            #pragma unroll
            for (int oo = 0; oo < 16; ++oo)
              wk = fmaf(w2r[oo], w1[(o0 + oo) * 48 + k], wk);  // uniform -> s_load
            wloc10[s] += wk;                 // same per-(s,c) g-order as original
          }
      #pragma unroll
      for (int s = 0; s < 10; ++s) part[grp * 1920 + (s * 3 + c) * 64 + p] = wloc10[s];
    }
    float sb = 0.0f;
    #pragma unroll
    for (int oo = 0; oo < 16; ++oo) sb = fmaf(w2r[oo], b1[o0 + oo], sb);
    bpart[grp * 64 + p] = sb;
  }
  __syncthreads();

  // ---- phase 1: reduce partials -> wl/bl (exact original order); query setup ----
  for (int idx = tid; idx < 30 * 64; idx += 1024)
    wl[idx] = part[idx] + part[1920 + idx] + part[3840 + idx] + part[5760 + idx];
  if (tid < 64) {
    bl[tid] = b2[tid] + bpart[tid] + bpart[64 + tid] + bpart[128 + tid] + bpart[192 + tid];
    float qx = pb[nb + tid], qy = pb[nb + tid + NPTS], qz = pb[nb + tid + 2 * NPTS];
    half4 va = {(_Float16)(-2.0f * (float)(_Float16)qx),   // -2*f16(q): exact in f16
                (_Float16)(-2.0f * (float)(_Float16)qy),
                (_Float16)(-2.0f * (float)(_Float16)qz),
                (_Float16)1.0f};
    a4s[tid] = va;
    sqqs[tid] = fmaf(qz, qz, fmaf(qy, qy, qx * qx));
    cnt[tid] = 0;
  }
  __syncthreads();   // part dead from here on -> X region free

  // wave geometry: qt = query-tile (16 rows), ws covers 1024 points = 64 MFMA tiles
  const int qt = wv >> 2, ws = wv & 3, g = lane >> 4, col = lane & 15;
  const int base = ws * 1024;
  const int rowb = qt * 16 + g * 4;   // this lane's first C-row
  half8 af;
  #pragma unroll
  for (int j = 0; j < 8; ++j) af[j] = (_Float16)0.0f;
  if (g == 0) {
    half4 aq = a4s[qt * 16 + col];    // A row = col index here (row = lane&15)
    af[0] = aq[0]; af[1] = aq[1]; af[2] = aq[2]; af[3] = aq[3];
  }
  f32x4 zz;
  #pragma unroll
  for (int j = 0; j < 4; ++j) zz[j] = 0.0f;

  // ---- pass 1: MFMA keys, running min per C-reg ----
  float mreg[4];
  #pragma unroll
  for (int j = 0; j < 4; ++j) mreg[j] = INFINITY;
  #pragma unroll 2
  for (int t = 0; t < 64; ++t) {
    half4 bp = pts4[base + t * 16 + col];
    half8 bf;
    bf[0] = bp[0]; bf[1] = bp[1]; bf[2] = bp[2]; bf[3] = bp[3];
    bf[4] = bp[0]; bf[5] = bp[1]; bf[6] = bp[2]; bf[7] = bp[3];
    f32x4 acc = __builtin_amdgcn_mfma_f32_16x16x32_f16(af, bf, zz, 0, 0, 0);
    #pragma unroll
    for (int j = 0; j < 4; ++j) mreg[j] = fminf(mreg[j], acc[j]);
  }
  // mreg[j] = min over this wave's 1024 pts at col -> unit-min (ws*16+col) of row rowb+j
  #pragma unroll
  for (int j = 0; j < 4; ++j)
    X[(rowb + j) * 65 + ws * 16 + col] = mreg[j];
  __syncthreads();

  // ---- tau: MSB-first radix-select over the row's 64 unit-mins (rows 4wv..4wv+3) ----
  unsigned um[4];
  #pragma unroll
  for (int r = 0; r < 4; ++r) {
    float dm = X[(4 * wv + r) * 65 + lane];
    unsigned ub = __float_as_uint(dm);
    um[r] = (ub & 0x80000000u) ? ~ub : (ub | 0x80000000u);
  }
  unsigned pfx0 = 0u, pfx1 = 0u, pfx2 = 0u, pfx3 = 0u;
  #pragma unroll 1
  for (int bno = 31; bno >= 8; --bno) {
    const unsigned bit = 1u << bno, ones = bit - 1u;
    if (__popcll(__ballot(um[0] <= (pfx0 | ones))) < NSMP) pfx0 |= bit;
    if (__popcll(__ballot(um[1] <= (pfx1 | ones))) < NSMP) pfx1 |= bit;
    if (__popcll(__ballot(um[2] <= (pfx2 | ones))) < NSMP) pfx2 |= bit;
    if (__popcll(__ballot(um[3] <= (pfx3 | ones))) < NSMP) pfx3 |= bit;
  }
  float tx[4];
  #pragma unroll
  for (int r = 0; r < 4; ++r) {
    unsigned T = ((r == 0) ? pfx0 : (r == 1) ? pfx1 : (r == 2) ? pfx2 : pfx3) | 0xFFu;
    unsigned tb = (T & 0x80000000u) ? (T ^ 0x80000000u) : ~T;
    float tf = __uint_as_float(tb);          // upper bound on 10th unit-min (mfma keys)
    float sqr = sqqs[4 * wv + r];
    float d10sq = tf + sqr;                  // key = |P-q|^2 - |q|^2  ->  d10^2 estimate
    if (d10sq < 0.0f) d10sq = 0.0f;
    float aq = sqrtf(sqr);
    float L = aq + sqrtf(d10sq) + 0.05f;
    float slack = 2e-3f + 0.00146484375f * (4.0f * aq * L + L * L);  // 3/2048 * (...)
    tx[r] = __fadd_rn(tf, slack);
  }
  if (lane == 0) {
    taub[4 * wv + 0] = tx[0]; taub[4 * wv + 1] = tx[1];
    taub[4 * wv + 2] = tx[2]; taub[4 * wv + 3] = tx[3];
  }
  __syncthreads();

  // ---- pass 2: bit-identical MFMA recompute, push survivors (block-level buffers) ----
  float tau4[4];
  #pragma unroll
  for (int j = 0; j < 4; ++j) tau4[j] = taub[rowb + j];
  int* bufi = (int*)X;
  #pragma unroll 2
  for (int t = 0; t < 64; ++t) {
    const int m0 = base + t * 16 + col;
    half4 bp = pts4[m0];
    half8 bf;
    bf[0] = bp[0]; bf[1] = bp[1]; bf[2] = bp[2]; bf[3] = bp[3];
    bf[4] = bp[0]; bf[5] = bp[1]; bf[6] = bp[2]; bf[7] = bp[3];
    f32x4 acc = __builtin_amdgcn_mfma_f32_16x16x32_f16(af, bf, zz, 0, 0, 0);
    #pragma unroll
    for (int j = 0; j < 4; ++j) {
      if (acc[j] <= tau4[j]) {
        const int row = rowb + j;
        int ps = atomicAdd(&cnt[row], 1);
        if (ps < 64) bufi[row * 64 + ps] = m0;
      }
    }
  }
  __syncthreads();

  // ---- pass 3: f64 re-rank, ROW-SERIAL SCALAR form ----
  #pragma unroll 1
  for (int r = 0; r < 4; ++r) {
    const int row = 4 * wv + r;
    int cr = __builtin_amdgcn_readfirstlane(cnt[row]);
    if (cr > 64) cr = 64;
    const int nq = nb + row;
    int sv = 0x7FFFFFFF;
    double dv = (double)INFINITY;
    if (lane < cr) {
      float qxf = pb[nq], qyf = pb[nq + NPTS], qzf = pb[nq + 2 * NPTS];
      sv = bufi[row * 64 + lane];
      float px = pb[sv], py = pb[sv + NPTS], pz = pb[sv + 2 * NPTS];
      double dqx = (double)qxf, dqy = (double)qyf, dqz = (double)qzf;
      double dpx = (double)px, dpy = (double)py, dpz = (double)pz;
      double dot = dqx * dpx + dqy * dpy + dqz * dpz;
      double sqn = dqx * dqx + dqy * dqy + dqz * dqz;
      double sqm = dpx * dpx + dpy * dpy + dpz * dpz;
      dv = (sqn - 2.0 * dot) + sqm;              // self -> exactly 0.0
    }
    int rank = 0;
    #pragma unroll 1
    for (int j = 0; j < cr; ++j) {
      int jlo = __builtin_amdgcn_readlane(__double2loint(dv), j);
      int jhi = __builtin_amdgcn_readlane(__double2hiint(dv), j);
      int ji  = __builtin_amdgcn_readlane(sv, j);
      double jd = __hiloint2double(jhi, jlo);
      if (jd < dv || (jd == dv && ji < sv)) ++rank;
    }
    if (lane < cr && rank < NSMP)
      nbrT[row][rank] = sv;
  }
  __syncthreads();   // bufi reads done before trans overwrite (X aliased)

  // ---- epilogue: MLP acc then per-wave transpose slice (exact f32 coords) ----
  float* transF = &X[wv * 260];
  #pragma unroll 1
  for (int r = 0; r < 4; ++r) {
    float a = bl[lane];
    #pragma unroll
    for (int s = 0; s < NSMP; ++s) {
      const int id = nbrT[4 * wv + r][s];  // uniform -> broadcast ds_read
      float px = pb[id], py = pb[id + NPTS], pz = pb[id + 2 * NPTS];  // L2-hot
      a = fmaf(wl[(s * 3 + 0) * 64 + lane], px, a);
      a = fmaf(wl[(s * 3 + 1) * 64 + lane], py, a);
      a = fmaf(wl[(s * 3 + 2) * 64 + lane], pz, a);
    }
    transF[r * 65 + lane] = a;            // padded row -> conflict-free
  }
  __syncthreads();

  // coalesced store: thread (p = tid>>4, t16 = tid&15) writes n = nb + 4*t16 .. +3
  {
    int p = tid >> 4, t16 = tid & 15;
    float4 v;
    v.x = X[t16 * 260 + 0 * 65 + p];
    v.y = X[t16 * 260 + 1 * 65 + p];
    v.z = X[t16 * 260 + 2 * 65 + p];
    v.w = X[t16 * 260 + 3 * 65 + p];
    *(float4*)(out + ((size_t)b * 64 + p) * NPTS + nb + 4 * t16) = v;
  }
}

extern "C" void kernel_launch(void* const* d_in, const int* in_sizes, int n_in,
                              void* d_out, int out_size, void* d_ws, size_t ws_size,
                              hipStream_t stream) {
  (void)in_sizes; (void)n_in; (void)out_size; (void)d_ws; (void)ws_size;
  const float* pos = (const float*)d_in[0];
  const float* w1  = (const float*)d_in[1];
  const float* b1  = (const float*)d_in[2];
  const float* w2  = (const float*)d_in[3];
  const float* b2  = (const float*)d_in[4];
  float* out = (float*)d_out;

  topk_kernel<<<dim3(64, 8), dim3(1024), 0, stream>>>(pos, w1, b1, w2, b2, out);
}

// Round 7
// 132.501 us; speedup vs baseline: 1.2438x; 1.2438x over previous
//
#include <hip/hip_runtime.h>
#include <math.h>

#define NPTS 4096
#define NSMP 10

typedef float f32x2 __attribute__((ext_vector_type(2)));

// ---------------- prep: fuse (w1,b1,w2,b2) -> Wn[30][64] ([s*3+c][p]), bb[64] ----------
// out[p] = bb[p] + sum_{s,c} Wn[s*3+c][p] * pos[b,c,idx_s]  (no nonlinearity -> legal).
// Kept as a SEPARATE kernel: R13's in-kernel fusion made every block serialize behind a
// 4-wave scalar-load fma chain (+28 us); as its own 1-block dispatch it costs ~8 us.
__global__ __launch_bounds__(256) void prep_kernel(
    const float* __restrict__ w1, const float* __restrict__ b1,
    const float* __restrict__ w2, const float* __restrict__ b2,
    float* __restrict__ wn, float* __restrict__ bb) {
  __shared__ float w1l[64 * 48];      // 12 KB, [o][k]
  __shared__ float w2t[64 * 64];      // 16 KB, transposed [o][p] (lane reads stride-1)
  __shared__ float b1l[64];
  __shared__ float part[4][30][64];   // 30 KB
  __shared__ float bpart[4][64];
  const int t = threadIdx.x, p = t & 63, grp = t >> 6, o0 = grp * 16;
  for (int idx = t; idx < 64 * 48; idx += 256) w1l[idx] = w1[idx];
  for (int idx = t; idx < 64 * 64; idx += 256) w2t[(idx & 63) * 64 + (idx >> 6)] = w2[idx];
  if (t < 64) b1l[t] = b1[t];
  __syncthreads();

  const int sg[16] = {0,2,4,6, 3,5,7,9, 1,3,5,7, 2,4,6,8};
  float w2r[16];
  #pragma unroll
  for (int oo = 0; oo < 16; ++oo) w2r[oo] = w2t[(o0 + oo) * 64 + p];
  float wloc[30];
  #pragma unroll
  for (int i = 0; i < 30; ++i) wloc[i] = 0.0f;
  #pragma unroll
  for (int g = 0; g < 4; ++g)
    #pragma unroll
    for (int i = 0; i < 2; ++i)
      #pragma unroll
      for (int j = 0; j < 2; ++j) {
        const int s = sg[g * 4 + i * 2 + j];
        #pragma unroll
        for (int c = 0; c < 3; ++c) {
          const int k = (c + 3 * g) * 4 + i * 2 + j;   // w1 flat index over (12,2,2)
          float wk = 0.0f;
          #pragma unroll
          for (int oo = 0; oo < 16; ++oo)
            wk = fmaf(w2r[oo], w1l[(o0 + oo) * 48 + k], wk);  // w1l read is broadcast
          wloc[s * 3 + c] += wk;
        }
      }
  #pragma unroll
  for (int i = 0; i < 30; ++i) part[grp][i][p] = wloc[i];
  float sb = 0.0f;
  #pragma unroll
  for (int oo = 0; oo < 16; ++oo) sb = fmaf(w2r[oo], b1l[o0 + oo], sb);
  bpart[grp][p] = sb;
  __syncthreads();
  const float* p0 = &part[0][0][0];
  for (int idx = t; idx < 30 * 64; idx += 256)
    wn[idx] = p0[idx] + p0[1920 + idx] + p0[3840 + idx] + p0[5760 + idx];
  if (t < 64) bb[t] = b2[t] + bpart[0][t] + bpart[1][t] + bpart[2][t] + bpart[3][t];
}

// ---------------- fused topk + mlp: R0 VALU filter + row-serial pass 3 ----------------
// Cross-round evidence: R0's VALU filter (70.7 us WITH 47 MB spill) beats every MFMA
// variant (78-88 us even spill-free) -> keep the VALU filter.  R0's spill: true VGPR
// need ~64+eps under the 64-reg budget of (1024,8); the marginal pressure is pass-3's
// fully-unrolled dd[4]/si[4]/rank[4] + 4x f64 temp sets (~16-20 VGPR) on top of the
// filter's ~45.  Fix: ROW-SERIAL SCALAR pass 3 (bit-identical: per-row j<cr ==
// R0's j<cmax since non-survivor lanes have dv=INF/sv=MAX and never increment rank).
// Everything else is R0 verbatim: 1024 threads, grid 64x8, LDS 74.75 KB (2 blocks/CU),
// f32x2 pair-packed filter, MSB-first radix-select tau, f64 re-rank, fused MLP.
__global__ __launch_bounds__(1024, 8) void topk_kernel(const float* __restrict__ pos,
                                                       const float* __restrict__ wng,
                                                       const float* __restrict__ bbg,
                                                       float* __restrict__ out) {
  __shared__ float pts3[NPTS * 3];    // 48 KB packed (x,y,z)
  __shared__ float trans[16 * 260];   // 16.25 KB; per-wave 260-float slice (alias: bufi)
  __shared__ float wl[30 * 64];       // 7.5 KB Wn
  __shared__ float bl[64];
  __shared__ int   nbrL[16][4][NSMP]; // 2.5 KB
  __shared__ int   cnt[16][4];

  const int b = blockIdx.y, tid = threadIdx.x, lane = tid & 63, wv = tid >> 6;
  const float* pb = pos + (size_t)b * 3 * NPTS;
  for (int i = tid; i < NPTS; i += 1024) {
    pts3[3 * i + 0] = pb[i];
    pts3[3 * i + 1] = pb[i + NPTS];
    pts3[3 * i + 2] = pb[i + 2 * NPTS];
  }
  for (int i = tid; i < 30 * 64; i += 1024) wl[i] = wng[i];
  if (tid < 64) bl[tid] = bbg[tid];
  __syncthreads();

  const int nb = blockIdx.x * 64;       // block's first row
  const int n0 = nb + wv * 4;           // wave's first row
  float* transF = &trans[wv * 260];     // this wave's private slice
  int*   bufiW  = (int*)transF;         // survivor buffer: r*64+slot (256 ints <= 260)

  // 4 queries, pair-packed, -2 folded (filter-only arithmetic)
  f32x2 qx2[2], qy2[2], qz2[2], dmin[2];
  #pragma unroll
  for (int pp = 0; pp < 2; ++pp) {
    int na = n0 + 2 * pp;
    qx2[pp].x = -2.0f * pts3[3 * na + 0]; qx2[pp].y = -2.0f * pts3[3 * na + 3];
    qy2[pp].x = -2.0f * pts3[3 * na + 1]; qy2[pp].y = -2.0f * pts3[3 * na + 4];
    qz2[pp].x = -2.0f * pts3[3 * na + 2]; qz2[pp].y = -2.0f * pts3[3 * na + 5];
    dmin[pp].x = INFINITY; dmin[pp].y = INFINITY;
  }

  // ---- pass 1: per-row lane minima ----
  #pragma unroll 2
  for (int k = 0; k < 64; ++k) {
    int m = k * 64 + lane;
    float x = pts3[3 * m], y = pts3[3 * m + 1], z = pts3[3 * m + 2];
    float sq = fmaf(z, z, fmaf(y, y, x * x));
    f32x2 sq2; sq2.x = sq; sq2.y = sq;
    #pragma unroll
    for (int pp = 0; pp < 2; ++pp) {
      f32x2 key = qx2[pp] * x + sq2;
      key = qy2[pp] * y + key;
      key = qz2[pp] * z + key;
      dmin[pp] = __builtin_elementwise_min(dmin[pp], key);
    }
  }

  // ---- tau: MSB-first radix-select; prefix is wave-uniform (SGPRs) ----
  unsigned um[4];
  #pragma unroll
  for (int r = 0; r < 4; ++r) {
    float dm = (r & 1) ? dmin[r >> 1].y : dmin[r >> 1].x;
    unsigned ub = __float_as_uint(dm);
    um[r] = (ub & 0x80000000u) ? ~ub : (ub | 0x80000000u);
  }
  unsigned pfx0 = 0u, pfx1 = 0u, pfx2 = 0u, pfx3 = 0u;
  #pragma unroll 1
  for (int bno = 31; bno >= 8; --bno) {
    const unsigned bit = 1u << bno, ones = bit - 1u;
    if (__popcll(__ballot(um[0] <= (pfx0 | ones))) < NSMP) pfx0 |= bit;
    if (__popcll(__ballot(um[1] <= (pfx1 | ones))) < NSMP) pfx1 |= bit;
    if (__popcll(__ballot(um[2] <= (pfx2 | ones))) < NSMP) pfx2 |= bit;
    if (__popcll(__ballot(um[3] <= (pfx3 | ones))) < NSMP) pfx3 |= bit;
  }
  float tx[4];
  #pragma unroll
  for (int r = 0; r < 4; ++r) {
    unsigned T = ((r == 0) ? pfx0 : (r == 1) ? pfx1 : (r == 2) ? pfx2 : pfx3) | 0xFFu;
    unsigned tb = (T & 0x80000000u) ? (T ^ 0x80000000u) : ~T;
    float tf = __uint_as_float(tb);
    tx[r] = __fadd_rn(__fadd_rn(tf, 2e-4f), __fmul_rn(fabsf(tf), 1e-5f));
  }

  if (lane < 4) cnt[wv][lane] = 0;     // same-wave DS ops are in-order

  // ---- pass 2: recompute keys (identical formula), push survivors ----
  #pragma unroll 2
  for (int k = 0; k < 64; ++k) {
    int m = k * 64 + lane;
    float x = pts3[3 * m], y = pts3[3 * m + 1], z = pts3[3 * m + 2];
    float sq = fmaf(z, z, fmaf(y, y, x * x));
    f32x2 sq2; sq2.x = sq; sq2.y = sq;
    #pragma unroll
    for (int pp = 0; pp < 2; ++pp) {
      f32x2 key = qx2[pp] * x + sq2;
      key = qy2[pp] * y + key;
      key = qz2[pp] * z + key;
      if (key.x <= tx[2 * pp]) {
        int ps = atomicAdd(&cnt[wv][2 * pp], 1);
        if (ps < 64) bufiW[(2 * pp) * 64 + ps] = m;
      }
      if (key.y <= tx[2 * pp + 1]) {
        int ps = atomicAdd(&cnt[wv][2 * pp + 1], 1);
        if (ps < 64) bufiW[(2 * pp + 1) * 64 + ps] = m;
      }
    }
  }

  // ---- pass 3: f64 re-rank, ROW-SERIAL SCALAR form (register diet) ----
  // Bit-identical to the array form: for j in [cr,cmax) the compare was always false
  // (jd=INF==dv=INF -> ji<sv false; survivors have finite dv), so per-row j<cr is
  // the same rank.  Scalar dv/sv/rank die per-row -> ~16-20 fewer concurrent VGPRs.
  #pragma unroll 1
  for (int r = 0; r < 4; ++r) {
    int cr = __builtin_amdgcn_readfirstlane(cnt[wv][r]);
    if (cr > 64) cr = 64;
    const int nq = n0 + r;
    int sv = 0x7FFFFFFF;
    double dv = (double)INFINITY;
    if (lane < cr) {
      float qxf = pts3[3 * nq], qyf = pts3[3 * nq + 1], qzf = pts3[3 * nq + 2];
      sv = bufiW[r * 64 + lane];
      float px = pts3[3 * sv], py = pts3[3 * sv + 1], pz = pts3[3 * sv + 2];
      double dqx = (double)qxf, dqy = (double)qyf, dqz = (double)qzf;
      double dpx = (double)px, dpy = (double)py, dpz = (double)pz;
      double dot = dqx * dpx + dqy * dpy + dqz * dpz;
      double sqn = dqx * dqx + dqy * dqy + dqz * dqz;
      double sqm = dpx * dpx + dpy * dpy + dpz * dpz;
      dv = (sqn - 2.0 * dot) + sqm;              // self -> exactly 0.0
    }
    int rank = 0;
    #pragma unroll 1
    for (int j = 0; j < cr; ++j) {
      int jlo = __builtin_amdgcn_readlane(__double2loint(dv), j);
      int jhi = __builtin_amdgcn_readlane(__double2hiint(dv), j);
      int ji  = __builtin_amdgcn_readlane(sv, j);
      double jd = __hiloint2double(jhi, jlo);
      if (jd < dv || (jd == dv && ji < sv)) ++rank;
    }
    if (lane < cr && rank < NSMP)
      nbrL[wv][r][rank] = sv;
  }

  // ---- epilogue: acc then per-wave transpose slice (bufiW is dead now) ----
  #pragma unroll 1
  for (int r = 0; r < 4; ++r) {
    float a = bl[lane];
    #pragma unroll
    for (int s = 0; s < NSMP; ++s) {
      int id = nbrL[wv][r][s];          // uniform -> broadcast ds_read
      float px = pts3[3 * id], py = pts3[3 * id + 1], pz = pts3[3 * id + 2];
      a = fmaf(wl[(s * 3 + 0) * 64 + lane], px, a);
      a = fmaf(wl[(s * 3 + 1) * 64 + lane], py, a);
      a = fmaf(wl[(s * 3 + 2) * 64 + lane], pz, a);
    }
    transF[r * 65 + lane] = a;          // padded row -> conflict-free
  }
  __syncthreads();

  // coalesced store: thread (p = tid>>4, t16 = tid&15) writes n = nb + 4*t16 .. +3
  {
    int p = tid >> 4, t16 = tid & 15;
    float4 v;
    v.x = trans[t16 * 260 + 0 * 65 + p];
    v.y = trans[t16 * 260 + 1 * 65 + p];
    v.z = trans[t16 * 260 + 2 * 65 + p];
    v.w = trans[t16 * 260 + 3 * 65 + p];
    *(float4*)(out + ((size_t)b * 64 + p) * NPTS + nb + 4 * t16) = v;
  }
}

extern "C" void kernel_launch(void* const* d_in, const int* in_sizes, int n_in,
                              void* d_out, int out_size, void* d_ws, size_t ws_size,
                              hipStream_t stream) {
  (void)in_sizes; (void)n_in; (void)out_size; (void)ws_size;
  const float* pos = (const float*)d_in[0];
  const float* w1  = (const float*)d_in[1];
  const float* b1  = (const float*)d_in[2];
  const float* w2  = (const float*)d_in[3];
  const float* b2  = (const float*)d_in[4];
  float* out = (float*)d_out;

  // workspace: Wn (30*64 f32) then bb (64 f32)
  float* wn = (float*)d_ws;
  float* bb = (float*)((char*)d_ws + 30 * 64 * 4);

  prep_kernel<<<dim3(1), dim3(256), 0, stream>>>(w1, b1, w2, b2, wn, bb);
  topk_kernel<<<dim3(64, 8), dim3(1024), 0, stream>>>(pos, wn, bb, out);
}